// Round 6
// baseline (465.371 us; speedup 1.0000x reference)
//
#include <hip/hip_runtime.h>
#include <hip/hip_bf16.h>

// KMeans predict: ids = argmin_k ||c_k||^2 - 2 x.c_k    (N=500000, D=64, K=1024)
// Pass 0: fp64 ||c||^2 table (pass2's authority).
// Pass 1: 32x32x16 f16 MFMA, A=centers (LDS hi), B=points (regs hi+lo).
//         C operand = -0.5||c||^2 loaded as ONE aligned 64B LDS vector (no
//         element-wise init -> no AGPR shuttle). Per-slot running top-2 with
//         5-bit ctl packed into score mantissa (4 VALU/score).
//         gap < MARGIN -> uncertain list.
// Pass 2: fp64-exact BLOCK-per-point, THREAD-per-center (no inner-loop
//         shuffles; one reduction per point).

#define N_PTS 500000
#define DIM   64
#define K_CENT 1024
#define MARGIN 8.0e-3f   // ~7 sigma of c-lo truncation noise (~1.1e-3 rms)

typedef _Float16 half8    __attribute__((ext_vector_type(8)));
typedef float    floatx16 __attribute__((ext_vector_type(16)));

// ---------------------------------------------------------------- pass 0 ----
__global__ void kmeans_m2pre(const float* __restrict__ centers,
                             double* __restrict__ m2d)
{
    const int c = blockIdx.x * 256 + threadIdx.x;
    if (c >= K_CENT) return;
    const float4* crow = (const float4*)(centers + (size_t)c * DIM);
    double s = 0.0;
    #pragma unroll
    for (int kc = 0; kc < 16; ++kc) {
        float4 v = crow[kc];
        double a = v.x, b = v.y, cc = v.z, d = v.w;
        s += a * a + b * b + cc * cc + d * d;
    }
    m2d[c] = s;
}

// ---------------------------------------------------------------- pass 1 ----
// 512 threads = 8 waves; each wave owns 32 points (one 32-col C tile).
// Centers staged fp16(hi) to LDS in 4 stages of 256, row stride 72 halves
// (144 B - measured 0 bank conflicts). nmv = -0.5||c||^2 pre-permuted into
// C-operand order: nmv[ctl][h][reg] = negm2[ctl*32 + (reg&3)+8*(reg>>2)+4h].
__launch_bounds__(512, 4)
__global__ void kmeans_pass1(const float* __restrict__ x,
                             const float* __restrict__ centers,
                             int* __restrict__ out,
                             int* __restrict__ counter,
                             int* __restrict__ ulist,
                             int capacity)
{
    __shared__ __align__(16) _Float16 ldsC[256 * 72];   // 36.9 KB
    __shared__ __align__(64) float nmv[8][2][16];       // 1 KB, C-operand order

    const int tid  = threadIdx.x;
    const int lane = tid & 63;
    const int wave = tid >> 6;
    const int col  = lane & 31;      // point within wave's 32
    const int h    = lane >> 5;      // row-group selector (C/D layout)

    const int p  = blockIdx.x * 256 + wave * 32 + col;
    const int pc = p > N_PTS - 1 ? N_PTS - 1 : p;       // tail clamp (dup)

    // ---- B fragments (points), hi+lo: B[k = c*16 + h*8 + j][n = col] ----
    half8 bh[4], bl[4];
    {
        const float* xr = x + (size_t)pc * DIM + h * 8;
        #pragma unroll
        for (int c = 0; c < 4; ++c) {
            float4 f0 = *(const float4*)(xr + c * 16);
            float4 f1 = *(const float4*)(xr + c * 16 + 4);
            float v[8] = {f0.x, f0.y, f0.z, f0.w, f1.x, f1.y, f1.z, f1.w};
            half8 hi, lo;
            #pragma unroll
            for (int j = 0; j < 8; ++j) {
                _Float16 hj = (_Float16)v[j];
                hi[j] = hj;
                lo[j] = (_Float16)(v[j] - (float)hj);   // exact residual
            }
            bh[c] = hi; bl[c] = lo;
        }
    }

    // per-slot running best (M) and runner-up (S), packed ctl in low 5 bits
    float M[16], S[16];
    #pragma unroll
    for (int i = 0; i < 16; ++i) { M[i] = -3.0e38f; S[i] = -3.0e38f; }

    for (int s = 0; s < 4; ++s) {
        __syncthreads();                                 // prev-stage readers
        // ---- stage 256 centers: thread t -> center t>>1, half t&1 ----
        {
            const int c = tid >> 1, hh = tid & 1;
            const float* src = centers + (size_t)(s * 256 + c) * DIM + hh * 32;
            float ss = 0.f;
            #pragma unroll
            for (int g = 0; g < 4; ++g) {
                float4 f0 = *(const float4*)(src + g * 8);
                float4 f1 = *(const float4*)(src + g * 8 + 4);
                float v[8] = {f0.x, f0.y, f0.z, f0.w, f1.x, f1.y, f1.z, f1.w};
                half8 hi;
                #pragma unroll
                for (int j = 0; j < 8; ++j) {
                    ss = fmaf(v[j], v[j], ss);
                    hi[j] = (_Float16)v[j];
                }
                *(half8*)&ldsC[c * 72 + hh * 32 + g * 8] = hi;
            }
            float oss = __shfl_xor(ss, 1);
            if (hh == 0) {
                // scatter -0.5||c||^2 into C-operand order
                const int lr  = c & 31;                  // local row in tile
                const int ctl = c >> 5;
                const int hv  = (lr >> 2) & 1;
                const int reg = (lr & 3) + ((lr >> 3) << 2);
                nmv[ctl][hv][reg] = -0.5f * (ss + oss);
            }
        }
        __syncthreads();

        // ---- 8 center-tiles of 32 in this stage ----
        for (int ctl = 0; ctl < 8; ++ctl) {
            const int ct = s * 8 + ctl;
            // C operand: one aligned 64B LDS vector (broadcast across lanes)
            floatx16 acc = *(const floatx16*)&nmv[ctl][h][0];

            // A fragments (centers): A[m = ctl*32+col][k = c*16 + h*8 + j]
            const _Float16* ap = &ldsC[(ctl * 32 + col) * 72 + h * 8];
            #pragma unroll
            for (int c = 0; c < 4; ++c) {
                half8 a = *(const half8*)(ap + c * 16);
                acc = __builtin_amdgcn_mfma_f32_32x32x16_f16(a, bh[c], acc, 0, 0, 0);
                acc = __builtin_amdgcn_mfma_f32_32x32x16_f16(a, bl[c], acc, 0, 0, 0);
            }

            // ---- per-slot running top-2, ctl packed in low 5 mantissa bits ----
            #pragma unroll
            for (int i = 0; i < 16; ++i) {
                unsigned u = (__float_as_uint(acc[i]) & 0xFFFFFFE0u) | (unsigned)ct;
                float k = __uint_as_float(u);
                S[i] = fmaxf(S[i], fminf(k, M[i]));
                M[i] = fmaxf(M[i], k);
            }
        }
    }

    // ---- epilogue: top-2 across 16 slots, decode, merge halves, write ----
    {
        float s1 = M[0], s2 = -3.0e38f;
        int   w  = 0;
        #pragma unroll
        for (int i = 1; i < 16; ++i) {
            float t = M[i];
            s2 = fmaxf(s2, fminf(t, s1));
            bool gt = t > s1;
            s1 = gt ? t : s1;
            w  = gt ? i : w;
        }
        float Sw = S[0];
        #pragma unroll
        for (int i = 1; i < 16; ++i) Sw = (i == w) ? S[i] : Sw;
        s2 = fmaxf(s2, Sw);

        int ct  = (int)(__float_as_uint(s1) & 31u);
        int row = (w & 3) + 8 * (w >> 2) + 4 * h;
        int cid = ct * 32 + row;

        // merge the two row-groups (lanes l and l^32 hold same point col)
        float o1 = __shfl_xor(s1, 32);
        float o2 = __shfl_xor(s2, 32);
        int  ocid = __shfl_xor(cid, 32);
        float nm2 = fmaxf(fmaxf(s2, o2), fminf(s1, o1));
        bool take = o1 > s1;
        float nm1 = take ? o1 : s1;
        int  ncid = take ? ocid : cid;

        if (h == 0 && p < N_PTS) {
            out[p] = ncid;
            if (nm1 - nm2 < MARGIN) {                    // too close -> fp64
                int slot = atomicAdd(counter, 1);
                if (slot < capacity) ulist[slot] = p;
            }
        }
    }
}

// ---------------------------------------------------------------- pass 2 ----
// fp64-exact, BLOCK (1024 thr) per point, THREAD per center. x row staged in
// LDS (broadcast); each thread one full fp64 dot; single reduction per point.
__launch_bounds__(1024)
__global__ void kmeans_pass2(const float* __restrict__ x,
                             const float* __restrict__ centers,
                             const double* __restrict__ m2d,
                             int* __restrict__ out,
                             const int* __restrict__ counter,
                             const int* __restrict__ ulist,
                             int capacity)
{
    __shared__ float xs[64];
    __shared__ double wv[16];
    __shared__ int    wi[16];

    int count = *counter;
    if (count > capacity) count = capacity;
    const int tid  = threadIdx.x;
    const int lane = tid & 63;
    const int wave = tid >> 6;

    for (int u = blockIdx.x; u < count; u += gridDim.x) {
        __syncthreads();                               // protect xs/wv reuse
        const int p = ulist[u];
        if (tid < 16)
            ((float4*)xs)[tid] = ((const float4*)(x + (size_t)p * DIM))[tid];
        __syncthreads();

        const int c = tid;                             // one center per thread
        const float4* crow = (const float4*)(centers + (size_t)c * DIM);
        double dot = 0.0;
        #pragma unroll
        for (int kc = 0; kc < 16; ++kc) {
            float4 cv = crow[kc];
            float4 xv = *(const float4*)&xs[kc * 4];   // LDS broadcast
            dot += (double)cv.x * (double)xv.x + (double)cv.y * (double)xv.y
                 + (double)cv.z * (double)xv.z + (double)cv.w * (double)xv.w;
        }
        double bv = m2d[c] - 2.0 * dot;
        int    bi = c;

        #pragma unroll
        for (int m = 1; m <= 32; m <<= 1) {            // one reduce per point
            double ov = __shfl_xor(bv, m);
            int    oi = __shfl_xor(bi, m);
            if (ov < bv || (ov == bv && oi < bi)) { bv = ov; bi = oi; }
        }
        if (lane == 0) { wv[wave] = bv; wi[wave] = bi; }
        __syncthreads();
        if (tid == 0) {
            double v = wv[0]; int i = wi[0];
            #pragma unroll
            for (int w = 1; w < 16; ++w) {
                if (wv[w] < v || (wv[w] == v && wi[w] < i)) { v = wv[w]; i = wi[w]; }
            }
            out[p] = i;
        }
    }
}

extern "C" void kernel_launch(void* const* d_in, const int* in_sizes, int n_in,
                              void* d_out, int out_size, void* d_ws, size_t ws_size,
                              hipStream_t stream)
{
    const float* x       = (const float*)d_in[0];
    const float* centers = (const float*)d_in[1];
    int*    out     = (int*)d_out;
    int*    counter = (int*)d_ws;
    double* m2d     = (double*)((char*)d_ws + 1024);
    int*    ulist   = (int*)((char*)d_ws + 1024 + 8192);
    int capacity = (int)((ws_size > 9216 + 64 ? ws_size - 9216 : 0) / sizeof(int));
    if (capacity > N_PTS) capacity = N_PTS;

    hipMemsetAsync(d_ws, 0, 64, stream);
    kmeans_m2pre<<<4, 256, 0, stream>>>(centers, m2d);
    dim3 g1((N_PTS + 255) / 256);     // 1954 blocks x 512 threads, 256 pts each
    kmeans_pass1<<<g1, 512, 0, stream>>>(x, centers, out, counter, ulist, capacity);
    kmeans_pass2<<<2048, 1024, 0, stream>>>(x, centers, m2d, out, counter, ulist, capacity);
}